// Round 1
// baseline (3779.526 us; speedup 1.0000x reference)
//
#include <hip/hip_runtime.h>

// ---------------------------------------------------------------------------
// RegressionGRU: only h_last of LAYER 0 feeds the output head. Layer 1 is dead
// code in the reference. We run a persistent-RNN kernel: 32 WGs x 256 threads,
// each WG owns 16 batch rows (one MFMA M-tile) for all 512 time steps.
// w_hh (bf16 B-fragments) is register-resident: 12 N-tiles x 8 K-steps x
// short8 = 384 VGPRs/lane. h lives in LDS (fp32, padded stride). No inter-WG
// communication of any kind.
// ---------------------------------------------------------------------------

typedef __attribute__((ext_vector_type(8))) short short8;
typedef __attribute__((ext_vector_type(4))) float floatx4;

#define T_LEN 512
#define I_DIM 64
#define H_DIM 256
#define NB 16        // batch rows per workgroup (one MFMA M-tile)
#define NWG 32       // 512 / 16
#define HPAD 260     // h LDS row stride in floats (+4 pad: conflict-free frags)

__device__ __forceinline__ unsigned short f2bf(float f) {
    union { float f; unsigned u; } v; v.f = f;
    // round-to-nearest-even bf16
    return (unsigned short)((v.u + 0x7FFFu + ((v.u >> 16) & 1u)) >> 16);
}

__device__ __forceinline__ short8 pack8v(floatx4 a, floatx4 b) {
    short8 r;
    r[0] = (short)f2bf(a[0]); r[1] = (short)f2bf(a[1]);
    r[2] = (short)f2bf(a[2]); r[3] = (short)f2bf(a[3]);
    r[4] = (short)f2bf(b[0]); r[5] = (short)f2bf(b[1]);
    r[6] = (short)f2bf(b[2]); r[7] = (short)f2bf(b[3]);
    return r;
}

// one-time: w_ih0 fp32 [768x64] -> bf16 bits in workspace (96 KB, L2-resident)
__global__ void cvt_wih_kernel(const float* __restrict__ w,
                               unsigned short* __restrict__ o) {
    int i = blockIdx.x * 256 + threadIdx.x;
    if (i < 768 * 64) o[i] = f2bf(w[i]);
}

__global__ __launch_bounds__(256, 1) void gru_kernel(
    const float* __restrict__ x,        // [512, 512, 64]
    const float* __restrict__ w_hh,     // [768, 256]
    const float* __restrict__ b_ih,     // [768]
    const float* __restrict__ b_hh,     // [768]
    const unsigned short* __restrict__ wih_bf, // [768, 64] bf16 bits
    const float* __restrict__ w_lin,    // [256]
    const float* __restrict__ b_lin,    // [1]
    float* __restrict__ out)            // [1024]
{
    __shared__ __align__(16) float h_lds[NB * HPAD]; // fp32 hidden state
    __shared__ float bias_rz[512];   // b_ih+b_hh for rows 0..511 (r,z)
    __shared__ float bias_n2[512];   // [0:256)=b_hh n-rows, [256:512)=b_ih n-rows

    const int tid  = threadIdx.x;
    const int wave = tid >> 6;       // 0..3, owns 64 hidden units
    const int lane = tid & 63;
    const int m16  = lane & 15;      // MFMA n-index / batch row for A-frag
    const int quad = lane >> 4;      // MFMA k-octet selector
    const int wg   = blockIdx.x;

    for (int i = tid; i < NB * HPAD; i += 256) h_lds[i] = 0.0f;  // h0 = 0
    for (int i = tid; i < 512; i += 256) bias_rz[i] = b_ih[i] + b_hh[i];
    for (int i = tid; i < 256; i += 256) {
        bias_n2[i]       = b_hh[512 + i];
        bias_n2[256 + i] = b_ih[512 + i];
    }

    // ---- persistent w_hh B-fragments (bf16), 12 N-tiles x 8 K-steps -------
    // tile g: gate type g>>2 (0=r,1=z,2=n), units wave*64 + (g&3)*16 + n
    short8 whh[12][8];
    #pragma unroll
    for (int g = 0; g < 12; ++g) {
        const int row = (g >> 2) * 256 + wave * 64 + (g & 3) * 16 + m16;
        const float* rp = w_hh + row * H_DIM;
        #pragma unroll
        for (int k = 0; k < 8; ++k) {
            const float* p = rp + k * 32 + quad * 8;
            whh[g][k] = pack8v(*(const floatx4*)p, *(const floatx4*)(p + 4));
        }
    }
    __syncthreads();

    const float* xrow = x + (long)(wg * NB + m16) * T_LEN * I_DIM + quad * 8;

    #pragma unroll 1
    for (int t = 0; t < T_LEN; ++t) {
        floatx4 acc[12];   // 0..3: r (x+h), 4..7: z (x+h), 8..11: hn (h only)
        floatx4 xn[4];     // xn (x only) - kept separate for n = tanh(xn + r*hn)
        #pragma unroll
        for (int g = 0; g < 8; ++g) {
            float bv = bias_rz[(g >> 2) * 256 + wave * 64 + (g & 3) * 16 + m16];
            acc[g] = (floatx4){bv, bv, bv, bv};
        }
        #pragma unroll
        for (int i = 0; i < 4; ++i) {
            float bh = bias_n2[wave * 64 + i * 16 + m16];
            float bx = bias_n2[256 + wave * 64 + i * 16 + m16];
            acc[8 + i] = (floatx4){bh, bh, bh, bh};
            xn[i]      = (floatx4){bx, bx, bx, bx};
        }

        // ---- hg: h @ w_hh^T, A-frags from LDS (fp32 -> bf16) -------------
        #pragma unroll
        for (int k = 0; k < 8; ++k) {
            const float* hp = h_lds + m16 * HPAD + k * 32 + quad * 8;
            short8 af = pack8v(*(const floatx4*)hp, *(const floatx4*)(hp + 4));
            #pragma unroll
            for (int g = 0; g < 12; ++g)
                acc[g] = __builtin_amdgcn_mfma_f32_16x16x32_bf16(
                             af, whh[g][k], acc[g], 0, 0, 0);
        }

        // ---- xg: x_t @ w_ih^T, A-frags from global x, B-frags streamed ---
        const float* xt = xrow + t * I_DIM;
        #pragma unroll
        for (int kx = 0; kx < 2; ++kx) {
            short8 xa = pack8v(*(const floatx4*)(xt + kx * 32),
                               *(const floatx4*)(xt + kx * 32 + 4));
            #pragma unroll
            for (int g = 0; g < 12; ++g) {
                const int row = (g >> 2) * 256 + wave * 64 + (g & 3) * 16 + m16;
                short8 bf = *(const short8*)(wih_bf + row * I_DIM + kx * 32 + quad * 8);
                if (g < 8)
                    acc[g] = __builtin_amdgcn_mfma_f32_16x16x32_bf16(
                                 xa, bf, acc[g], 0, 0, 0);
                else
                    xn[g - 8] = __builtin_amdgcn_mfma_f32_16x16x32_bf16(
                                    xa, bf, xn[g - 8], 0, 0, 0);
            }
        }
        __syncthreads();   // all waves done reading old h

        // ---- gates + h update (lane-local in C-layout) -------------------
        // C-layout: col(unit)=lane&15, row(batch)=quad*4+reg
        #pragma unroll
        for (int i = 0; i < 4; ++i) {
            const int u = wave * 64 + i * 16 + m16;
            #pragma unroll
            for (int r = 0; r < 4; ++r) {
                const int m = quad * 4 + r;
                float rr = 1.0f / (1.0f + __expf(-acc[i][r]));
                float zz = 1.0f / (1.0f + __expf(-acc[4 + i][r]));
                float av = xn[i][r] + rr * acc[8 + i][r];
                float nn = 1.0f - 2.0f / (1.0f + __expf(2.0f * av)); // tanh
                float ho = h_lds[m * HPAD + u];
                h_lds[m * HPAD + u] = (1.0f - zz) * nn + zz * ho;
            }
        }
        __syncthreads();   // h_new visible before next step's A-frag reads
    }

    // ---- output head: p = sigmoid(h . w_lin + b), out[2b]=p, out[2b+1]=1-p
    const int bl = tid >> 4, j = tid & 15;  // 16 threads per batch row
    float s = 0.0f;
    #pragma unroll
    for (int i = 0; i < 16; ++i) {
        const int c = j + i * 16;
        s += h_lds[bl * HPAD + c] * w_lin[c];
    }
    #pragma unroll
    for (int d = 8; d > 0; d >>= 1) s += __shfl_down(s, d, 16);
    if (j == 0) {
        float p = 1.0f / (1.0f + __expf(-(s + b_lin[0])));
        const int b = wg * NB + bl;
        out[2 * b]     = p;
        out[2 * b + 1] = 1.0f - p;
    }
}

extern "C" void kernel_launch(void* const* d_in, const int* in_sizes, int n_in,
                              void* d_out, int out_size, void* d_ws, size_t ws_size,
                              hipStream_t stream) {
    const float* x     = (const float*)d_in[0];
    const float* w_ih0 = (const float*)d_in[1];
    const float* w_hh0 = (const float*)d_in[2];
    const float* b_ih0 = (const float*)d_in[3];
    const float* b_hh0 = (const float*)d_in[4];
    // d_in[5..8]: layer-1 params -- dead code in the reference, never needed
    const float* w_lin = (const float*)d_in[9];
    const float* b_lin = (const float*)d_in[10];
    float* out = (float*)d_out;
    unsigned short* wih_bf = (unsigned short*)d_ws;  // 96 KB of workspace

    cvt_wih_kernel<<<192, 256, 0, stream>>>(w_ih0, wih_bf);
    gru_kernel<<<NWG, 256, 0, stream>>>(x, w_hh0, b_ih0, b_hh0, wih_bf,
                                        w_lin, b_lin, out);
}

// Round 2
// 3290.572 us; speedup vs baseline: 1.1486x; 1.1486x over previous
//
#include <hip/hip_runtime.h>

// ---------------------------------------------------------------------------
// RegressionGRU round 2. Only layer-0's final hidden state feeds the output;
// layer 1 of the reference is dead code. Persistent-RNN: 32 WGs x 512 threads
// (8 waves). Each WG owns 16 batch rows for all 512 steps; each wave owns 32
// hidden units x 3 gates = 6 MFMA N-tiles.
//
// Round-1 failure: whh[12][8] needed 384 VGPRs -> massive spill (VGPR=256,
// WRITE_SIZE 9.2MB of spill stores, 7.3us/step). Fix: 8 waves x 6 tiles =
// 192 VGPRs of weights. h kept bf16 in LDS in blocked MFMA-read order
// (conflict-free ds_read_b128), fp32 recurrence value in thread registers
// (each thread owns the same 8 (batch,unit) elements every step, by C-layout).
// w_ih preloaded once into LDS (96KB blocked). One barrier/step (dbuf h).
// ---------------------------------------------------------------------------

typedef __attribute__((ext_vector_type(8))) short short8;
typedef __attribute__((ext_vector_type(4))) float floatx4;

#define T_LEN 512
#define I_DIM 64
#define H_DIM 256
#define NB 16      // batch rows per WG (one MFMA M-tile)
#define NWG 32     // 512 / 16

__device__ __forceinline__ unsigned short f2bf(float f) {
    union { float f; unsigned u; } v; v.f = f;
    return (unsigned short)((v.u + 0x7FFFu + ((v.u >> 16) & 1u)) >> 16);
}

__device__ __forceinline__ short8 pack8v(floatx4 a, floatx4 b) {
    short8 r;
    r[0] = (short)f2bf(a[0]); r[1] = (short)f2bf(a[1]);
    r[2] = (short)f2bf(a[2]); r[3] = (short)f2bf(a[3]);
    r[4] = (short)f2bf(b[0]); r[5] = (short)f2bf(b[1]);
    r[6] = (short)f2bf(b[2]); r[7] = (short)f2bf(b[3]);
    return r;
}

__device__ __forceinline__ float sigm(float a) {
    return 1.0f / (1.0f + __expf(-a));
}

__global__ __launch_bounds__(512, 2) void gru_kernel(
    const float* __restrict__ x,        // [512, 512, 64]
    const float* __restrict__ w_ih,     // [768, 64]
    const float* __restrict__ w_hh,     // [768, 256]
    const float* __restrict__ b_ih,     // [768]
    const float* __restrict__ b_hh,     // [768]
    const float* __restrict__ w_lin,    // [256]
    const float* __restrict__ b_lin,    // [1]
    float* __restrict__ out)            // [1024]
{
    // 96KB wih (blocked bf16) + 16KB h double-buffer (blocked bf16).
    __shared__ __align__(16) unsigned short wih_lds[6144 * 8]; // 96 KB
    __shared__ __align__(16) unsigned short hbf[1024 * 8];     // 16 KB

    const int tid  = threadIdx.x;
    const int wave = tid >> 6;       // 0..7: owns units wave*32..wave*32+31
    const int lane = tid & 63;
    const int m16  = lane & 15;      // batch row (A) / unit-in-tile (B/C col)
    const int quad = lane >> 4;      // K-octet selector / C row-group
    const int wg   = blockIdx.x;

    // ---- preload w_ih -> LDS, blocked: block ((w*6+g)*2+kx)*64 + lane -----
    // g = gate*2 + i  (gate 0=r,1=z,2=n; i = 16-unit subtile 0/1)
    for (int b = tid; b < 6144; b += 512) {
        const int l  = b & 63;
        const int kx = (b >> 6) & 1;
        const int g  = (b >> 7) % 6;
        const int w  = (b >> 7) / 6;
        const int row = (g >> 1) * 256 + w * 32 + (g & 1) * 16 + (l & 15);
        const int col = kx * 32 + (l >> 4) * 8;
        const float* p = w_ih + row * I_DIM + col;
        *(short8*)&wih_lds[b * 8] = pack8v(*(const floatx4*)p,
                                           *(const floatx4*)(p + 4));
    }
    // zero both h buffers (h0 = 0)
    for (int b = tid; b < 1024; b += 512)
        *(short8*)&hbf[b * 8] = (short8)0;

    // ---- persistent w_hh B-fragments: 6 tiles x 8 K-steps = 192 VGPRs ----
    // tile order: 0=r/i0 1=r/i1 2=z/i0 3=z/i1 4=n/i0 5=n/i1
    short8 whh[6][8];
    #pragma unroll
    for (int g = 0; g < 6; ++g) {
        const int row = (g >> 1) * 256 + wave * 32 + (g & 1) * 16 + m16;
        const float* rp = w_hh + row * H_DIM;
        #pragma unroll
        for (int k = 0; k < 8; ++k) {
            const float* p = rp + k * 32 + quad * 8;
            whh[g][k] = pack8v(*(const floatx4*)p, *(const floatx4*)(p + 4));
        }
    }

    // ---- biases (registers, per-lane) ------------------------------------
    float brz[4], bhn[2], bxn[2];
    #pragma unroll
    for (int g = 0; g < 4; ++g) {
        const int u = wave * 32 + (g & 1) * 16 + m16;
        brz[g] = b_ih[(g >> 1) * 256 + u] + b_hh[(g >> 1) * 256 + u];
    }
    #pragma unroll
    for (int i = 0; i < 2; ++i) {
        const int u = wave * 32 + i * 16 + m16;
        bhn[i] = b_hh[512 + u];
        bxn[i] = b_ih[512 + u];
    }

    float h_old[8] = {0, 0, 0, 0, 0, 0, 0, 0};  // fp32 recurrence state

    const float* xrow = x + (long)(wg * NB + m16) * T_LEN * I_DIM + quad * 8;

    __syncthreads();

    #pragma unroll 1
    for (int t = 0; t < T_LEN; ++t) {
        floatx4 acc[4], an[2], xnl[2];
        #pragma unroll
        for (int g = 0; g < 4; ++g)
            acc[g] = (floatx4){brz[g], brz[g], brz[g], brz[g]};
        #pragma unroll
        for (int i = 0; i < 2; ++i) {
            an[i]  = (floatx4){bhn[i], bhn[i], bhn[i], bhn[i]};
            xnl[i] = (floatx4){bxn[i], bxn[i], bxn[i], bxn[i]};
        }

        // ---- hg: h @ w_hh^T (A-frags: conflict-free blocked ds_read_b128)
        const unsigned short* hb = &hbf[(t & 1) * 512 * 8];
        #pragma unroll
        for (int k = 0; k < 8; ++k) {
            short8 af = *(const short8*)&hb[(k * 64 + lane) * 8];
            acc[0] = __builtin_amdgcn_mfma_f32_16x16x32_bf16(af, whh[0][k], acc[0], 0, 0, 0);
            acc[1] = __builtin_amdgcn_mfma_f32_16x16x32_bf16(af, whh[1][k], acc[1], 0, 0, 0);
            acc[2] = __builtin_amdgcn_mfma_f32_16x16x32_bf16(af, whh[2][k], acc[2], 0, 0, 0);
            acc[3] = __builtin_amdgcn_mfma_f32_16x16x32_bf16(af, whh[3][k], acc[3], 0, 0, 0);
            an[0]  = __builtin_amdgcn_mfma_f32_16x16x32_bf16(af, whh[4][k], an[0], 0, 0, 0);
            an[1]  = __builtin_amdgcn_mfma_f32_16x16x32_bf16(af, whh[5][k], an[1], 0, 0, 0);
        }

        // ---- xg: x_t @ w_ih^T (A from global, B from LDS) ----------------
        const float* xt = xrow + t * I_DIM;
        #pragma unroll
        for (int kx = 0; kx < 2; ++kx) {
            short8 xa = pack8v(*(const floatx4*)(xt + kx * 32),
                               *(const floatx4*)(xt + kx * 32 + 4));
            const unsigned short* wb =
                &wih_lds[(((wave * 6) * 2 + kx) * 64 + lane) * 8];
            // tiles g are 128-blocks apart: ((w*6+g)*2+kx)*64 strides g by 128
            acc[0] = __builtin_amdgcn_mfma_f32_16x16x32_bf16(xa, *(const short8*)&wb[0 * 128 * 8], acc[0], 0, 0, 0);
            acc[1] = __builtin_amdgcn_mfma_f32_16x16x32_bf16(xa, *(const short8*)&wb[1 * 128 * 8], acc[1], 0, 0, 0);
            acc[2] = __builtin_amdgcn_mfma_f32_16x16x32_bf16(xa, *(const short8*)&wb[2 * 128 * 8], acc[2], 0, 0, 0);
            acc[3] = __builtin_amdgcn_mfma_f32_16x16x32_bf16(xa, *(const short8*)&wb[3 * 128 * 8], acc[3], 0, 0, 0);
            xnl[0] = __builtin_amdgcn_mfma_f32_16x16x32_bf16(xa, *(const short8*)&wb[4 * 128 * 8], xnl[0], 0, 0, 0);
            xnl[1] = __builtin_amdgcn_mfma_f32_16x16x32_bf16(xa, *(const short8*)&wb[5 * 128 * 8], xnl[1], 0, 0, 0);
        }

        // ---- gates + h update (lane-local; C-layout col=m16, row=quad*4+r)
        unsigned short* hbn = &hbf[((t + 1) & 1) * 512 * 8];
        #pragma unroll
        for (int i = 0; i < 2; ++i) {
            #pragma unroll
            for (int r = 0; r < 4; ++r) {
                const int idx = i * 4 + r;
                float rr = sigm(acc[i][r]);          // r-gate
                float zz = sigm(acc[2 + i][r]);      // z-gate
                float av = xnl[i][r] + rr * an[i][r];
                float nn = 1.0f - 2.0f / (1.0f + __expf(2.0f * av)); // tanh
                float hn = (1.0f - zz) * nn + zz * h_old[idx];
                h_old[idx] = hn;
                // unit u = wave*32 + i*16 + m16 -> block k=wave,
                // quad_u = i*2 + (m16>>3), elem j = m16&7, row = quad*4+r
                hbn[(wave * 64 + (i * 2 + (m16 >> 3)) * 16 + quad * 4 + r) * 8
                    + (m16 & 7)] = f2bf(hn);
            }
        }
        __syncthreads();  // h(t+1) visible; prev buffer free for overwrite
    }

    // ---- epilogue: p = sigmoid(h_last . w_lin + b) -----------------------
    __syncthreads();
    float* hfin = (float*)hbf;  // reuse 16KB as fp32 h[16][256]
    #pragma unroll
    for (int i = 0; i < 2; ++i)
        #pragma unroll
        for (int r = 0; r < 4; ++r)
            hfin[(quad * 4 + r) * 256 + wave * 32 + i * 16 + m16] =
                h_old[i * 4 + r];
    __syncthreads();

    const int m = tid >> 5, j = tid & 31;  // 32 threads per batch row
    float s = 0.0f;
    #pragma unroll
    for (int c = 0; c < 8; ++c)
        s += hfin[m * 256 + j + c * 32] * w_lin[j + c * 32];
    #pragma unroll
    for (int d = 16; d > 0; d >>= 1) s += __shfl_down(s, d, 32);
    if (j == 0) {
        float p = sigm(s + b_lin[0]);
        const int b = wg * NB + m;
        out[2 * b]     = p;
        out[2 * b + 1] = 1.0f - p;
    }
}

extern "C" void kernel_launch(void* const* d_in, const int* in_sizes, int n_in,
                              void* d_out, int out_size, void* d_ws, size_t ws_size,
                              hipStream_t stream) {
    const float* x     = (const float*)d_in[0];
    const float* w_ih0 = (const float*)d_in[1];
    const float* w_hh0 = (const float*)d_in[2];
    const float* b_ih0 = (const float*)d_in[3];
    const float* b_hh0 = (const float*)d_in[4];
    // d_in[5..8]: layer-1 params — dead code in the reference
    const float* w_lin = (const float*)d_in[9];
    const float* b_lin = (const float*)d_in[10];
    float* out = (float*)d_out;

    gru_kernel<<<NWG, 512, 0, stream>>>(x, w_ih0, w_hh0, b_ih0, b_hh0,
                                        w_lin, b_lin, out);
}

// Round 3
// 2303.407 us; speedup vs baseline: 1.6408x; 1.4286x over previous
//
#include <hip/hip_runtime.h>

// ---------------------------------------------------------------------------
// RegressionGRU round 3. Layer 1 of the reference is dead code; only layer-0's
// final hidden state feeds the output head. Persistent-RNN: 32 WGs x 512
// threads (8 waves), each WG owns 16 batch rows for all 512 steps; each wave
// owns 32 hidden units x 3 gates = 6 MFMA N-tiles (whh register-resident).
//
// R2 failure: __launch_bounds__(512,2) -> toolchain treats arg2 as BLOCKS/CU
// -> 4 waves/EU -> 128-VGPR cap vs ~250 needed -> ~130 regs spilled, per-step
// scratch reloads via L2 (invisible in HBM counters), 6.4us/step.
// Fix: __launch_bounds__(512,1) -> 2 waves/EU -> 256-VGPR cap, and trim live
// set under 256: biases in LDS (per-thread contiguous, 2 ds_read_b128/step),
// acc zero-init with bias added at gate-eval, x loaded in kx halves (8 raw
// floats live during hg, not 16).
// ---------------------------------------------------------------------------

typedef __attribute__((ext_vector_type(8))) short short8;
typedef __attribute__((ext_vector_type(4))) float floatx4;

#define T_LEN 512
#define I_DIM 64
#define H_DIM 256
#define NB 16      // batch rows per WG (one MFMA M-tile)
#define NWG 32     // 512 / 16

__device__ __forceinline__ unsigned short f2bf(float f) {
    union { float f; unsigned u; } v; v.f = f;
    return (unsigned short)((v.u + 0x7FFFu + ((v.u >> 16) & 1u)) >> 16);
}

__device__ __forceinline__ short8 pack8v(floatx4 a, floatx4 b) {
    short8 r;
    r[0] = (short)f2bf(a[0]); r[1] = (short)f2bf(a[1]);
    r[2] = (short)f2bf(a[2]); r[3] = (short)f2bf(a[3]);
    r[4] = (short)f2bf(b[0]); r[5] = (short)f2bf(b[1]);
    r[6] = (short)f2bf(b[2]); r[7] = (short)f2bf(b[3]);
    return r;
}

__device__ __forceinline__ float sigm(float a) {
    return 1.0f / (1.0f + __expf(-a));
}

__global__ __launch_bounds__(512, 1) void gru_kernel(
    const float* __restrict__ x,        // [512, 512, 64]
    const float* __restrict__ w_ih,     // [768, 64]
    const float* __restrict__ w_hh,     // [768, 256]
    const float* __restrict__ b_ih,     // [768]
    const float* __restrict__ b_hh,     // [768]
    const float* __restrict__ w_lin,    // [256]
    const float* __restrict__ b_lin,    // [1]
    float* __restrict__ out)            // [1024]
{
    __shared__ __align__(16) unsigned short wih_lds[6144 * 8]; // 96 KB
    __shared__ __align__(16) unsigned short hbf[1024 * 8];     // 16 KB dbuf
    __shared__ __align__(16) float bias_lds[512 * 8];          // 16 KB

    const int tid  = threadIdx.x;
    const int wave = tid >> 6;       // 0..7: owns units wave*32..wave*32+31
    const int lane = tid & 63;
    const int m16  = lane & 15;      // batch row (A) / unit-in-tile (B/C col)
    const int quad = lane >> 4;      // K-octet selector / C row-group
    const int wg   = blockIdx.x;

    // ---- preload w_ih -> LDS, blocked: block ((w*6+g)*2+kx)*64 + lane -----
    for (int b = tid; b < 6144; b += 512) {
        const int l  = b & 63;
        const int kx = (b >> 6) & 1;
        const int g  = (b >> 7) % 6;
        const int w  = (b >> 7) / 6;
        const int row = (g >> 1) * 256 + w * 32 + (g & 1) * 16 + (l & 15);
        const int col = kx * 32 + (l >> 4) * 8;
        const float* p = w_ih + row * I_DIM + col;
        *(short8*)&wih_lds[b * 8] = pack8v(*(const floatx4*)p,
                                           *(const floatx4*)(p + 4));
    }
    for (int b = tid; b < 1024; b += 512)
        *(short8*)&hbf[b * 8] = (short8)0;   // h0 = 0 (both buffers)

    // ---- per-thread bias vector (contiguous 32B): frees 8 VGPRs ----------
    {
        const int u0 = wave * 32 + m16, u1 = u0 + 16;
        float* bl = &bias_lds[tid * 8];
        bl[0] = b_ih[u0] + b_hh[u0];               // r  i0
        bl[1] = b_ih[u1] + b_hh[u1];               // r  i1
        bl[2] = b_ih[256 + u0] + b_hh[256 + u0];   // z  i0
        bl[3] = b_ih[256 + u1] + b_hh[256 + u1];   // z  i1
        bl[4] = b_hh[512 + u0];                    // hn i0
        bl[5] = b_hh[512 + u1];                    // hn i1
        bl[6] = b_ih[512 + u0];                    // xn i0
        bl[7] = b_ih[512 + u1];                    // xn i1
    }

    // ---- persistent w_hh B-fragments: 6 tiles x 8 K-steps = 192 VGPRs ----
    short8 whh[6][8];
    #pragma unroll
    for (int g = 0; g < 6; ++g) {
        const int row = (g >> 1) * 256 + wave * 32 + (g & 1) * 16 + m16;
        const float* rp = w_hh + row * H_DIM;
        #pragma unroll
        for (int k = 0; k < 8; ++k) {
            const float* p = rp + k * 32 + quad * 8;
            whh[g][k] = pack8v(*(const floatx4*)p, *(const floatx4*)(p + 4));
        }
    }

    float h_old[8] = {0, 0, 0, 0, 0, 0, 0, 0};  // fp32 recurrence carry

    const float* xbase = x + (long)(wg * NB + m16) * T_LEN * I_DIM + quad * 8;
    const unsigned short* wb0 =
        &wih_lds[(((wave * 6) * 2 + 0) * 64 + lane) * 8];
    const unsigned short* wb1 =
        &wih_lds[(((wave * 6) * 2 + 1) * 64 + lane) * 8];

    __syncthreads();

    #pragma unroll 1
    for (int t = 0; t < T_LEN; ++t) {
        const float* xt = xbase + t * I_DIM;
        // kx=0 x half: issue now, consumed after hg (latency hidden by MFMA)
        floatx4 x0 = *(const floatx4*)(xt);
        floatx4 x1 = *(const floatx4*)(xt + 4);

        floatx4 acc[4], an[2], xnl[2];
        #pragma unroll
        for (int g = 0; g < 4; ++g) acc[g] = (floatx4){0, 0, 0, 0};
        an[0] = an[1] = xnl[0] = xnl[1] = (floatx4){0, 0, 0, 0};

        // ---- hg: h @ w_hh^T (A-frags: conflict-free blocked ds_read_b128)
        const unsigned short* hb = &hbf[(t & 1) * 512 * 8];
        #pragma unroll
        for (int k = 0; k < 8; ++k) {
            short8 af = *(const short8*)&hb[(k * 64 + lane) * 8];
            acc[0] = __builtin_amdgcn_mfma_f32_16x16x32_bf16(af, whh[0][k], acc[0], 0, 0, 0);
            acc[1] = __builtin_amdgcn_mfma_f32_16x16x32_bf16(af, whh[1][k], acc[1], 0, 0, 0);
            acc[2] = __builtin_amdgcn_mfma_f32_16x16x32_bf16(af, whh[2][k], acc[2], 0, 0, 0);
            acc[3] = __builtin_amdgcn_mfma_f32_16x16x32_bf16(af, whh[3][k], acc[3], 0, 0, 0);
            an[0]  = __builtin_amdgcn_mfma_f32_16x16x32_bf16(af, whh[4][k], an[0], 0, 0, 0);
            an[1]  = __builtin_amdgcn_mfma_f32_16x16x32_bf16(af, whh[5][k], an[1], 0, 0, 0);
        }

        // ---- xg kx=0 ------------------------------------------------------
        short8 xa = pack8v(x0, x1);
        // issue kx=1 half while kx=0 MFMAs run
        x0 = *(const floatx4*)(xt + 32);
        x1 = *(const floatx4*)(xt + 36);
        acc[0] = __builtin_amdgcn_mfma_f32_16x16x32_bf16(xa, *(const short8*)&wb0[0 * 128 * 8], acc[0], 0, 0, 0);
        acc[1] = __builtin_amdgcn_mfma_f32_16x16x32_bf16(xa, *(const short8*)&wb0[1 * 128 * 8], acc[1], 0, 0, 0);
        acc[2] = __builtin_amdgcn_mfma_f32_16x16x32_bf16(xa, *(const short8*)&wb0[2 * 128 * 8], acc[2], 0, 0, 0);
        acc[3] = __builtin_amdgcn_mfma_f32_16x16x32_bf16(xa, *(const short8*)&wb0[3 * 128 * 8], acc[3], 0, 0, 0);
        xnl[0] = __builtin_amdgcn_mfma_f32_16x16x32_bf16(xa, *(const short8*)&wb0[4 * 128 * 8], xnl[0], 0, 0, 0);
        xnl[1] = __builtin_amdgcn_mfma_f32_16x16x32_bf16(xa, *(const short8*)&wb0[5 * 128 * 8], xnl[1], 0, 0, 0);

        // ---- xg kx=1 ------------------------------------------------------
        xa = pack8v(x0, x1);
        acc[0] = __builtin_amdgcn_mfma_f32_16x16x32_bf16(xa, *(const short8*)&wb1[0 * 128 * 8], acc[0], 0, 0, 0);
        acc[1] = __builtin_amdgcn_mfma_f32_16x16x32_bf16(xa, *(const short8*)&wb1[1 * 128 * 8], acc[1], 0, 0, 0);
        acc[2] = __builtin_amdgcn_mfma_f32_16x16x32_bf16(xa, *(const short8*)&wb1[2 * 128 * 8], acc[2], 0, 0, 0);
        acc[3] = __builtin_amdgcn_mfma_f32_16x16x32_bf16(xa, *(const short8*)&wb1[3 * 128 * 8], acc[3], 0, 0, 0);
        xnl[0] = __builtin_amdgcn_mfma_f32_16x16x32_bf16(xa, *(const short8*)&wb1[4 * 128 * 8], xnl[0], 0, 0, 0);
        xnl[1] = __builtin_amdgcn_mfma_f32_16x16x32_bf16(xa, *(const short8*)&wb1[5 * 128 * 8], xnl[1], 0, 0, 0);

        // ---- gates + h update (lane-local; C: col=m16, row=quad*4+r) -----
        floatx4 bv0 = *(const floatx4*)&bias_lds[tid * 8];
        floatx4 bv1 = *(const floatx4*)&bias_lds[tid * 8 + 4];
        unsigned short* hbn = &hbf[((t + 1) & 1) * 512 * 8];
        #pragma unroll
        for (int i = 0; i < 2; ++i) {
            #pragma unroll
            for (int r = 0; r < 4; ++r) {
                const int idx = i * 4 + r;
                float rr = sigm(acc[i][r] + bv0[i]);
                float zz = sigm(acc[2 + i][r] + bv0[2 + i]);
                float av = xnl[i][r] + bv1[2 + i] + rr * (an[i][r] + bv1[i]);
                float nn = 1.0f - 2.0f / (1.0f + __expf(2.0f * av)); // tanh
                float hn = (1.0f - zz) * nn + zz * h_old[idx];
                h_old[idx] = hn;
                hbn[(wave * 64 + (i * 2 + (m16 >> 3)) * 16 + quad * 4 + r) * 8
                    + (m16 & 7)] = f2bf(hn);
            }
        }
        __syncthreads();  // h(t+1) visible; prev buffer free for overwrite
    }

    // ---- epilogue: p = sigmoid(h_last . w_lin + b) -----------------------
    __syncthreads();
    float* hfin = (float*)hbf;  // reuse 16KB as fp32 h[16][256]
    #pragma unroll
    for (int i = 0; i < 2; ++i)
        #pragma unroll
        for (int r = 0; r < 4; ++r)
            hfin[(quad * 4 + r) * 256 + wave * 32 + i * 16 + m16] =
                h_old[i * 4 + r];
    __syncthreads();

    const int m = tid >> 5, j = tid & 31;  // 32 threads per batch row
    float s = 0.0f;
    #pragma unroll
    for (int c = 0; c < 8; ++c)
        s += hfin[m * 256 + j + c * 32] * w_lin[j + c * 32];
    #pragma unroll
    for (int d = 16; d > 0; d >>= 1) s += __shfl_down(s, d, 32);
    if (j == 0) {
        float p = sigm(s + b_lin[0]);
        const int b = wg * NB + m;
        out[2 * b]     = p;
        out[2 * b + 1] = 1.0f - p;
    }
}

extern "C" void kernel_launch(void* const* d_in, const int* in_sizes, int n_in,
                              void* d_out, int out_size, void* d_ws, size_t ws_size,
                              hipStream_t stream) {
    const float* x     = (const float*)d_in[0];
    const float* w_ih0 = (const float*)d_in[1];
    const float* w_hh0 = (const float*)d_in[2];
    const float* b_ih0 = (const float*)d_in[3];
    const float* b_hh0 = (const float*)d_in[4];
    // d_in[5..8]: layer-1 params — dead code in the reference
    const float* w_lin = (const float*)d_in[9];
    const float* b_lin = (const float*)d_in[10];
    float* out = (float*)d_out;

    gru_kernel<<<NWG, 512, 0, stream>>>(x, w_ih0, w_hh0, b_ih0, b_hh0,
                                        w_lin, b_lin, out);
}

// Round 5
// 1852.410 us; speedup vs baseline: 2.0403x; 1.2435x over previous
//
#include <hip/hip_runtime.h>

// ---------------------------------------------------------------------------
// RegressionGRU round 5. Layer 1 of the reference is dead code; only layer-0's
// final hidden state feeds the output head. Persistent-RNN: 32 WGs x 512
// threads (8 waves); WG owns 16 batch rows for all 512 steps; wave owns 32
// hidden units x 3 gates.
//
// R2/R3 lesson: 512-thread block = 2 waves/SIMD => hard cap 256 regs/wave
// (unified VGPR+AGPR). Register budget by construction:
//   - whh r,z:   register-resident, 4 tiles x 8 k = 128 VGPRs
//   - whh n:     LDS, 8192 entries x 8 bf16 = 128 KB (R4 bug: sized/filled
//                4096 -> waves 4-7 read OOB garbage weights, absmax 9.6e-2)
//   - w_ih:      pre-swizzled bf16 in d_ws (96 KB, L2-resident; re-read each
//                step, issued at step top, hidden under the hg MFMA block)
//   - LDS total: 128K whn + 16K h double-buffer = 144K <= 160K
// Pipe budget/CU/step: MFMA 480x4.85=2328cyc, LDS ~200KB=~2350cyc -> ~1us/step.
// ---------------------------------------------------------------------------

typedef __attribute__((ext_vector_type(8))) short short8;
typedef __attribute__((ext_vector_type(4))) float floatx4;

#define T_LEN 512
#define I_DIM 64
#define H_DIM 256
#define NB 16      // batch rows per WG (one MFMA M-tile)
#define NWG 32     // 512 / 16

__device__ __forceinline__ unsigned short f2bf(float f) {
    union { float f; unsigned u; } v; v.f = f;
    return (unsigned short)((v.u + 0x7FFFu + ((v.u >> 16) & 1u)) >> 16);
}

__device__ __forceinline__ short8 pack8v(floatx4 a, floatx4 b) {
    short8 r;
    r[0] = (short)f2bf(a[0]); r[1] = (short)f2bf(a[1]);
    r[2] = (short)f2bf(a[2]); r[3] = (short)f2bf(a[3]);
    r[4] = (short)f2bf(b[0]); r[5] = (short)f2bf(b[1]);
    r[6] = (short)f2bf(b[2]); r[7] = (short)f2bf(b[3]);
    return r;
}

__device__ __forceinline__ float sigm(float a) {
    return 1.0f / (1.0f + __expf(-a));
}

// w_ih fp32 [768x64] -> bf16 in d_ws, blocked: block ((w*6+g)*2+kx)*64+lane,
// 8 bf16 per (block,lane). Same swizzle the main kernel consumes.
__global__ void cvt_wih_kernel(const float* __restrict__ w,
                               unsigned short* __restrict__ o) {
    int i = blockIdx.x * 256 + threadIdx.x;
    if (i < 6144) {
        const int l  = i & 63;
        const int kx = (i >> 6) & 1;
        const int g  = (i >> 7) % 6;
        const int wv = (i >> 7) / 6;
        const int row = (g >> 1) * 256 + wv * 32 + (g & 1) * 16 + (l & 15);
        const int col = kx * 32 + (l >> 4) * 8;
        const float* p = w + row * I_DIM + col;
        *(short8*)&o[i * 8] = pack8v(*(const floatx4*)p,
                                     *(const floatx4*)(p + 4));
    }
}

__global__ __launch_bounds__(512, 1) void gru_kernel(
    const float* __restrict__ x,        // [512, 512, 64]
    const float* __restrict__ w_hh,     // [768, 256]
    const float* __restrict__ b_ih,     // [768]
    const float* __restrict__ b_hh,     // [768]
    const unsigned short* __restrict__ wih_ws, // [6144*8] bf16, blocked
    const float* __restrict__ w_lin,    // [256]
    const float* __restrict__ b_lin,    // [1]
    float* __restrict__ out)            // [1024]
{
    // n-gate: 256 units x 256 k of bf16 = 8192 (block,lane) entries = 128 KB
    __shared__ __align__(16) unsigned short whn_lds[8192 * 8]; // 128 KB
    __shared__ __align__(16) unsigned short hbf[1024 * 8];     // 16 KB dbuf

    const int tid  = threadIdx.x;
    const int wave = tid >> 6;       // 0..7: owns units wave*32..wave*32+31
    const int lane = tid & 63;
    const int m16  = lane & 15;      // batch row (A) / unit-in-tile (B/C col)
    const int quad = lane >> 4;      // K-octet selector / C row-group
    const int wg   = blockIdx.x;

    // ---- preload whh n-gate -> LDS, blocked: block ((w*2+g)*8+k)*64+lane --
    for (int b = tid; b < 8192; b += 512) {
        const int l = b & 63;
        const int k = (b >> 6) & 7;
        const int g = (b >> 9) & 1;
        const int w = b >> 10;               // 0..7
        const int row = 512 + w * 32 + g * 16 + (l & 15);
        const int col = k * 32 + (l >> 4) * 8;
        const float* p = w_hh + row * H_DIM + col;
        *(short8*)&whn_lds[b * 8] = pack8v(*(const floatx4*)p,
                                           *(const floatx4*)(p + 4));
    }
    for (int b = tid; b < 1024; b += 512)
        *(short8*)&hbf[b * 8] = (short8)0;   // h0 = 0 (both buffers)

    // ---- persistent w_hh r,z B-fragments: 4 tiles x 8 K = 128 VGPRs ------
    // tile g: 0=r/i0 1=r/i1 2=z/i0 3=z/i1
    short8 whh[4][8];
    #pragma unroll
    for (int g = 0; g < 4; ++g) {
        const int row = (g >> 1) * 256 + wave * 32 + (g & 1) * 16 + m16;
        const float* rp = w_hh + row * H_DIM;
        #pragma unroll
        for (int k = 0; k < 8; ++k) {
            const float* p = rp + k * 32 + quad * 8;
            whh[g][k] = pack8v(*(const floatx4*)p, *(const floatx4*)(p + 4));
        }
    }

    // ---- biases in registers (8) ----------------------------------------
    float brz[4], bhn[2], bxn[2];
    #pragma unroll
    for (int g = 0; g < 4; ++g) {
        const int u = wave * 32 + (g & 1) * 16 + m16;
        brz[g] = b_ih[(g >> 1) * 256 + u] + b_hh[(g >> 1) * 256 + u];
    }
    #pragma unroll
    for (int i = 0; i < 2; ++i) {
        const int u = wave * 32 + i * 16 + m16;
        bhn[i] = b_hh[512 + u];
        bxn[i] = b_ih[512 + u];
    }

    float h_old[8] = {0, 0, 0, 0, 0, 0, 0, 0};  // fp32 recurrence carry

    const float* xbase = x + (long)(wg * NB + m16) * T_LEN * I_DIM + quad * 8;
    const unsigned short* wib = &wih_ws[(wave * 6 * 2 * 64 + lane) * 8];

    __syncthreads();

    #pragma unroll 1
    for (int t = 0; t < T_LEN; ++t) {
        // ---- issue global loads first (longest latency, hidden under hg) -
        const float* xt = xbase + t * I_DIM;
        floatx4 x0 = *(const floatx4*)(xt);
        floatx4 x1 = *(const floatx4*)(xt + 4);
        floatx4 x2 = *(const floatx4*)(xt + 32);
        floatx4 x3 = *(const floatx4*)(xt + 36);
        short8 wi[12];                         // L2-resident wih fragments
        #pragma unroll
        for (int j = 0; j < 12; ++j)           // block (wave*6+g)*2+kx, j=g*2+kx
            wi[j] = *(const short8*)&wib[j * 64 * 8];

        floatx4 acc[4], an[2], xnl[2];
        #pragma unroll
        for (int g = 0; g < 4; ++g) acc[g] = (floatx4){0, 0, 0, 0};
        an[0] = an[1] = xnl[0] = xnl[1] = (floatx4){0, 0, 0, 0};

        // ---- hg: h @ w_hh^T; r,z from registers, n from LDS --------------
        const unsigned short* hb = &hbf[(t & 1) * 512 * 8];
        const unsigned short* wnb = &whn_lds[(wave * 2 * 8 * 64 + lane) * 8];
        #pragma unroll
        for (int k = 0; k < 8; ++k) {
            short8 af  = *(const short8*)&hb[(k * 64 + lane) * 8];
            short8 wn0 = *(const short8*)&wnb[(k * 64) * 8];
            short8 wn1 = *(const short8*)&wnb[((8 + k) * 64) * 8];
            acc[0] = __builtin_amdgcn_mfma_f32_16x16x32_bf16(af, whh[0][k], acc[0], 0, 0, 0);
            acc[1] = __builtin_amdgcn_mfma_f32_16x16x32_bf16(af, whh[1][k], acc[1], 0, 0, 0);
            acc[2] = __builtin_amdgcn_mfma_f32_16x16x32_bf16(af, whh[2][k], acc[2], 0, 0, 0);
            acc[3] = __builtin_amdgcn_mfma_f32_16x16x32_bf16(af, whh[3][k], acc[3], 0, 0, 0);
            an[0]  = __builtin_amdgcn_mfma_f32_16x16x32_bf16(af, wn0, an[0], 0, 0, 0);
            an[1]  = __builtin_amdgcn_mfma_f32_16x16x32_bf16(af, wn1, an[1], 0, 0, 0);
        }

        // ---- xg: x_t @ w_ih^T --------------------------------------------
        short8 xa = pack8v(x0, x1);            // kx = 0
        acc[0] = __builtin_amdgcn_mfma_f32_16x16x32_bf16(xa, wi[0],  acc[0], 0, 0, 0);
        acc[1] = __builtin_amdgcn_mfma_f32_16x16x32_bf16(xa, wi[2],  acc[1], 0, 0, 0);
        acc[2] = __builtin_amdgcn_mfma_f32_16x16x32_bf16(xa, wi[4],  acc[2], 0, 0, 0);
        acc[3] = __builtin_amdgcn_mfma_f32_16x16x32_bf16(xa, wi[6],  acc[3], 0, 0, 0);
        xnl[0] = __builtin_amdgcn_mfma_f32_16x16x32_bf16(xa, wi[8],  xnl[0], 0, 0, 0);
        xnl[1] = __builtin_amdgcn_mfma_f32_16x16x32_bf16(xa, wi[10], xnl[1], 0, 0, 0);
        xa = pack8v(x2, x3);                   // kx = 1
        acc[0] = __builtin_amdgcn_mfma_f32_16x16x32_bf16(xa, wi[1],  acc[0], 0, 0, 0);
        acc[1] = __builtin_amdgcn_mfma_f32_16x16x32_bf16(xa, wi[3],  acc[1], 0, 0, 0);
        acc[2] = __builtin_amdgcn_mfma_f32_16x16x32_bf16(xa, wi[5],  acc[2], 0, 0, 0);
        acc[3] = __builtin_amdgcn_mfma_f32_16x16x32_bf16(xa, wi[7],  acc[3], 0, 0, 0);
        xnl[0] = __builtin_amdgcn_mfma_f32_16x16x32_bf16(xa, wi[9],  xnl[0], 0, 0, 0);
        xnl[1] = __builtin_amdgcn_mfma_f32_16x16x32_bf16(xa, wi[11], xnl[1], 0, 0, 0);

        // ---- gates + h update (lane-local; C: col=m16, row=quad*4+r) -----
        unsigned short* hbn = &hbf[((t + 1) & 1) * 512 * 8];
        #pragma unroll
        for (int i = 0; i < 2; ++i) {
            #pragma unroll
            for (int r = 0; r < 4; ++r) {
                const int idx = i * 4 + r;
                float rr = sigm(acc[i][r] + brz[i]);
                float zz = sigm(acc[2 + i][r] + brz[2 + i]);
                float av = xnl[i][r] + bxn[i] + rr * (an[i][r] + bhn[i]);
                float nn = 1.0f - 2.0f / (1.0f + __expf(2.0f * av)); // tanh
                float hn = (1.0f - zz) * nn + zz * h_old[idx];
                h_old[idx] = hn;
                hbn[(wave * 64 + (i * 2 + (m16 >> 3)) * 16 + quad * 4 + r) * 8
                    + (m16 & 7)] = f2bf(hn);
            }
        }
        __syncthreads();  // h(t+1) visible; prev buffer free for overwrite
    }

    // ---- epilogue: p = sigmoid(h_last . w_lin + b) -----------------------
    __syncthreads();
    float* hfin = (float*)hbf;  // reuse 16KB as fp32 h[16][256]
    #pragma unroll
    for (int i = 0; i < 2; ++i)
        #pragma unroll
        for (int r = 0; r < 4; ++r)
            hfin[(quad * 4 + r) * 256 + wave * 32 + i * 16 + m16] =
                h_old[i * 4 + r];
    __syncthreads();

    const int m = tid >> 5, j = tid & 31;  // 32 threads per batch row
    float s = 0.0f;
    #pragma unroll
    for (int c = 0; c < 8; ++c)
        s += hfin[m * 256 + j + c * 32] * w_lin[j + c * 32];
    #pragma unroll
    for (int d = 16; d > 0; d >>= 1) s += __shfl_down(s, d, 32);
    if (j == 0) {
        float p = sigm(s + b_lin[0]);
        const int b = wg * NB + m;
        out[2 * b]     = p;
        out[2 * b + 1] = 1.0f - p;
    }
}

extern "C" void kernel_launch(void* const* d_in, const int* in_sizes, int n_in,
                              void* d_out, int out_size, void* d_ws, size_t ws_size,
                              hipStream_t stream) {
    const float* x     = (const float*)d_in[0];
    const float* w_ih0 = (const float*)d_in[1];
    const float* w_hh0 = (const float*)d_in[2];
    const float* b_ih0 = (const float*)d_in[3];
    const float* b_hh0 = (const float*)d_in[4];
    // d_in[5..8]: layer-1 params — dead code in the reference
    const float* w_lin = (const float*)d_in[9];
    const float* b_lin = (const float*)d_in[10];
    float* out = (float*)d_out;
    unsigned short* wih_bf = (unsigned short*)d_ws;  // 96 KB of workspace

    cvt_wih_kernel<<<24, 256, 0, stream>>>(w_ih0, wih_bf);
    gru_kernel<<<NWG, 512, 0, stream>>>(x, w_hh0, b_ih0, b_hh0, wih_bf,
                                        w_lin, b_lin, out);
}